// Round 15
// baseline (233.482 us; speedup 1.0000x reference)
//
#include <hip/hip_runtime.h>
#include <math.h>

#define B_     2
#define L_     512
#define DM     768
#define DS     128
#define HD     64
#define DI     1536
#define NH     24
#define CONVD  1792
#define ZROW   3328
#define ML     (B_*L_)
#define Q      64
#define NC     (L_/Q)

typedef __bf16 bf16x8 __attribute__((ext_vector_type(8)));
typedef _Float16 h16x8 __attribute__((ext_vector_type(8)));
typedef float f32x4 __attribute__((ext_vector_type(4)));

__device__ __forceinline__ float sigmoidf_(float x){ return 1.f/(1.f+__expf(-x)); }
__device__ __forceinline__ ushort bf16rn(float x){
  uint u = __float_as_uint(x);
  u += 0x7fff + ((u>>16)&1);
  return (ushort)(u>>16);
}
__device__ __forceinline__ float bf2f(ushort h){ return __uint_as_float(((uint)h)<<16); }
__device__ __forceinline__ ushort f16rn(float x){
  _Float16 h = (_Float16)x;
  union { _Float16 f; ushort u; } cv; cv.f = h; return cv.u;
}
__device__ __forceinline__ void gll16(const void* g, void* l){
  __builtin_amdgcn_global_load_lds((const __attribute__((address_space(1))) void*)g,
                                   (__attribute__((address_space(3))) void*)l, 16, 0, 0);
}

// ---- one kernel: fp16-convert u, W_in[0:3328], W_out; fp32 dt-projection; zero d_out ----
__launch_bounds__(256)
__global__ void cvt_all(const float* __restrict__ u, const float* __restrict__ W_in,
                        const float* __restrict__ W_out,
                        ushort* __restrict__ uH, ushort* __restrict__ WinH,
                        ushort* __restrict__ WoutH, float* __restrict__ dtraw,
                        float* __restrict__ out, int outN4){
  const int N1 = ML*(DM/4);
  const int N2 = ZROW*(DM/4);
  const int N3 = DM*(DI/4);
  const int N4 = ML*NH;
  int idx = blockIdx.x*256 + threadIdx.x;
  if (idx < N1){
    int r = idx/(DM/4), c = (idx - r*(DM/4))<<2;
    float4 v = *(const float4*)&u[(size_t)r*DM + c];
    ushort h[4] = {f16rn(v.x), f16rn(v.y), f16rn(v.z), f16rn(v.w)};
    *(uint2*)&uH[(size_t)r*DM + c] = make_uint2((uint)h[0]|((uint)h[1]<<16), (uint)h[2]|((uint)h[3]<<16));
  } else if (idx < N1+N2){
    int li = idx - N1;
    int r = li/(DM/4), c = (li - r*(DM/4))<<2;
    float4 v = *(const float4*)&W_in[(size_t)r*DM + c];
    ushort h[4] = {f16rn(v.x), f16rn(v.y), f16rn(v.z), f16rn(v.w)};
    *(uint2*)&WinH[(size_t)r*DM + c] = make_uint2((uint)h[0]|((uint)h[1]<<16), (uint)h[2]|((uint)h[3]<<16));
  } else if (idx < N1+N2+N3){
    int li = idx - N1 - N2;
    int r = li/(DI/4), c = (li - r*(DI/4))<<2;
    float4 v = *(const float4*)&W_out[(size_t)r*DI + c];
    ushort h[4] = {f16rn(v.x), f16rn(v.y), f16rn(v.z), f16rn(v.w)};
    *(uint2*)&WoutH[(size_t)r*DI + c] = make_uint2((uint)h[0]|((uint)h[1]<<16), (uint)h[2]|((uint)h[3]<<16));
  } else if (idx < N1+N2+N3+N4){
    int li = idx - (N1+N2+N3);
    int m = li/NH, h = li - (li/NH)*NH;     // h-minor: 24 consecutive threads share u row
    const float* ur = u + (size_t)m*DM;
    const float* wr = W_in + (size_t)(ZROW + h)*DM;
    float acc = 0.f;
#pragma unroll 4
    for (int k=0; k<DM; k+=4){
      float4 a = *(const float4*)&ur[k];
      float4 b = *(const float4*)&wr[k];
      acc = fmaf(a.x,b.x, fmaf(a.y,b.y, fmaf(a.z,b.z, fmaf(a.w,b.w, acc))));
    }
    dtraw[(size_t)m*NH + h] = acc;
  } else {
    int o = idx - (N1+N2+N3+N4);
    if (o < outN4) *(float4*)&out[(size_t)o*4] = make_float4(0,0,0,0);
  }
}

// ---- fp16 single-plane GEMM: C[m][n] = sum_k A[m][k]*B[n][k], row stride = K halfs ----
template<int BM,int BN,int K,int SPLITK,bool ATOMIC>
__launch_bounds__(256, 2)
__global__ void gemm_f16(const ushort* __restrict__ AS, const ushort* __restrict__ BS,
                         float* __restrict__ C, int Nvalid, int Nstore){
  constexpr int KS = K / SPLITK;
  constexpr int STEPS = KS / 64;
  constexpr int WM=BM/2, WN=BN/2, FM=WM/16, FN=WN/16;
  __shared__ ushort Ah[2][BM*64], Bh[2][BN*64];
  const int tid=threadIdx.x, lane=tid&63, w=tid>>6;
  const int WR=w>>1, WC=w&1;
  const int bm=blockIdx.x*BM, bn=blockIdx.y*BN;
  const int kbase = blockIdx.z*KS;
  const int lr=lane&15;
  const int srow=lane>>3;
  const int scol=(((lane&7) ^ (srow&7))*8);
  f32x4 acc[FM][FN] = {};

  auto stage = [&](int d, int ks){
    int k0 = kbase + ks*64;
#pragma unroll
    for (int ci=w; ci<BM/8; ci+=4)
      gll16(&AS[(size_t)(bm + ci*8 + srow)*K + k0 + scol], &Ah[d][ci*512]);
#pragma unroll
    for (int ci=w; ci<BN/8; ci+=4)
      gll16(&BS[(size_t)(bn + ci*8 + srow)*K + k0 + scol], &Bh[d][ci*512]);
  };

  stage(0, 0);
  __syncthreads();
  int cur = 0;
  for (int ks=0; ks<STEPS; ks++){
    if (ks+1 < STEPS) stage(cur^1, ks+1);

    h16x8 af[2][FM], bf[2][FN];
#pragma unroll
    for (int s2=0;s2<2;s2++){
      int gslot = s2*4 + (lane>>4);
#pragma unroll
      for (int i=0;i<FM;i++){
        int R = WR*WM + i*16 + lr;
        af[s2][i] = *(const h16x8*)&Ah[cur][R*64 + (gslot ^ (lr&7))*8];
      }
#pragma unroll
      for (int j=0;j<FN;j++){
        int R = WC*WN + j*16 + lr;
        bf[s2][j] = *(const h16x8*)&Bh[cur][R*64 + (gslot ^ (lr&7))*8];
      }
    }
#pragma unroll
    for (int s2=0;s2<2;s2++)
#pragma unroll
      for (int i=0;i<FM;i++)
#pragma unroll
        for (int j=0;j<FN;j++)
          acc[i][j] = __builtin_amdgcn_mfma_f32_16x16x32_f16(af[s2][i], bf[s2][j], acc[i][j], 0,0,0);

    __syncthreads();
    cur ^= 1;
  }

#pragma unroll
  for (int i=0;i<FM;i++)
#pragma unroll
    for (int j=0;j<FN;j++){
      int n = bn + WC*WN + j*16 + lr;
      if (n < Nvalid){
#pragma unroll
        for (int e=0;e<4;e++){
          int m = bm + WR*WM + i*16 + (lane>>4)*4 + e;
          if (ATOMIC) atomicAdd(&C[(size_t)m*Nstore + n], acc[i][j][e]);
          else        C[(size_t)m*Nstore + n] = acc[i][j][e];
        }
      }
    }
}

// ---- rolling-window causal conv (width 4) + SiLU; 32 timesteps per block ----
__launch_bounds__(256)
__global__ void conv2_kernel(const float* __restrict__ zx,
                             const float* __restrict__ cw,
                             const float* __restrict__ cb,
                             float* __restrict__ xbc){
  int g = blockIdx.x;
  int c2 = blockIdx.y;
  int b = blockIdx.z;
  int t0g = c2*32;
  int ch = g*256 + threadIdx.x;
  const float* src = zx + (size_t)(b*L_ + t0g)*ZROW + DI + ch;
  float* dst = xbc + (size_t)(b*L_ + t0g)*CONVD + ch;
  float w0=cw[ch*4],w1=cw[ch*4+1],w2=cw[ch*4+2],w3=cw[ch*4+3],bias=cb[ch];
  float x0=0.f,x1=0.f,x2=0.f;
  if (t0g > 0){
    x0 = *(src - 3*ZROW);
    x1 = *(src - 2*ZROW);
    x2 = *(src - 1*ZROW);
  }
#pragma unroll 4
  for (int tt=0; tt<32; tt++){
    float xt = src[(size_t)tt*ZROW];
    float a = bias;
    a = fmaf(w3, xt, a); a = fmaf(w2, x2, a); a = fmaf(w1, x1, a); a = fmaf(w0, x0, a);
    dst[(size_t)tt*CONVD] = a * sigmoidf_(a);
    x0 = x1; x1 = x2; x2 = xt;
  }
}

// -------- K1 (MFMA): dt/cumsum (wave 0, from dtraw) + S_chunk[p][n] --------
__launch_bounds__(256)
__global__ void chunk_state_mfma(const float* __restrict__ dtraw,
                                 const float* __restrict__ xbc,
                                 const float* __restrict__ dt_bias,
                                 const float* __restrict__ A_log,
                                 float* __restrict__ dts, float* __restrict__ las,
                                 float* __restrict__ Schunk){
  constexpr int OX_HI=0, OX_LO=4096;
  constexpr int OB_HI=8192, OB_LO=16384;
  __shared__ ushort L[24576];
  __shared__ float Wt[64];
  int c=blockIdx.x, h=blockIdx.y, b=blockIdx.z;
  int tid=threadIdx.x;
  int bh=b*NH+h;
  const int tbase=bh*L_+c*Q;

  if (tid < 64){
    int t = c*Q + tid;
    float raw = dtraw[(size_t)(b*L_+t)*NH + h] + dt_bias[h];
    float dtv = raw > 20.f ? raw : log1pf(__expf(raw));
    float A = -__expf(A_log[h]);
    float la = dtv*A;
#pragma unroll
    for (int off=1; off<64; off<<=1){
      float v = __shfl_up(la, off);
      if (tid >= off) la += v;
    }
    dts[tbase + tid] = dtv;
    las[tbase + tid] = la;
    float la63 = __shfl(la, 63);
    Wt[tid] = __expf(la63 - la) * dtv;
  }
  __syncthreads();

  for (int it = tid; it < 64*16; it += 256){
    int s = it >> 4, p4 = (it & 15) << 2;
    float4 v = *(const float4*)&xbc[(size_t)(b*L_ + c*Q + s)*CONVD + h*HD + p4];
    float ws = Wt[s];
    float xv[4] = {v.x*ws, v.y*ws, v.z*ws, v.w*ws};
#pragma unroll
    for (int j=0;j<4;j++){
      int p = p4 + j;
      ushort hh = bf16rn(xv[j]);
      ushort ll = bf16rn(xv[j] - bf2f(hh));
      int idx = p*64 + (((s>>3) ^ (p&7))<<3) + (s&7);
      L[OX_HI + idx] = hh; L[OX_LO + idx] = ll;
    }
  }
  for (int it = tid; it < 64*32; it += 256){
    int s = it >> 5, n4 = (it & 31) << 2;
    float4 v = *(const float4*)&xbc[(size_t)(b*L_ + c*Q + s)*CONVD + DI + n4];
    float xv[4] = {v.x,v.y,v.z,v.w};
#pragma unroll
    for (int j=0;j<4;j++){
      int n = n4 + j;
      ushort hh = bf16rn(xv[j]);
      ushort ll = bf16rn(xv[j] - bf2f(hh));
      int idx = n*64 + (((s>>3) ^ (n&7))<<3) + (s&7);
      L[OB_HI + idx] = hh; L[OB_LO + idx] = ll;
    }
  }
  __syncthreads();

  const int lane = tid & 63, w = tid >> 6;
  const int wr = w >> 1, wc = w & 1;
  const int lr = lane & 15, lk = lane >> 4;
  f32x4 acc[2][4] = {};
#pragma unroll
  for (int ks=0; ks<2; ks++){
    bf16x8 ah[2], al[2], bhf[4], blf[4];
#pragma unroll
    for (int fi=0; fi<2; fi++){
      int R = wr*32 + fi*16 + lr;
      int idx = R*64 + (((ks*4 + lk) ^ (R&7))<<3);
      ah[fi] = *(const bf16x8*)&L[OX_HI + idx];
      al[fi] = *(const bf16x8*)&L[OX_LO + idx];
    }
#pragma unroll
    for (int fj=0; fj<4; fj++){
      int Rb = wc*64 + fj*16 + lr;
      int idx = Rb*64 + (((ks*4 + lk) ^ (Rb&7))<<3);
      bhf[fj] = *(const bf16x8*)&L[OB_HI + idx];
      blf[fj] = *(const bf16x8*)&L[OB_LO + idx];
    }
#pragma unroll
    for (int fi=0; fi<2; fi++)
#pragma unroll
      for (int fj=0; fj<4; fj++){
        acc[fi][fj] = __builtin_amdgcn_mfma_f32_16x16x32_bf16(ah[fi], bhf[fj], acc[fi][fj], 0,0,0);
        acc[fi][fj] = __builtin_amdgcn_mfma_f32_16x16x32_bf16(ah[fi], blf[fj], acc[fi][fj], 0,0,0);
        acc[fi][fj] = __builtin_amdgcn_mfma_f32_16x16x32_bf16(al[fi], bhf[fj], acc[fi][fj], 0,0,0);
      }
  }

  float* Sb = Schunk + ((size_t)bh*NC + c)*(HD*DS);
#pragma unroll
  for (int fi=0; fi<2; fi++)
#pragma unroll
    for (int fj=0; fj<4; fj++){
      int n = wc*64 + fj*16 + lr;
#pragma unroll
      for (int e=0; e<4; e++){
        int p = wr*32 + fi*16 + lk*4 + e;
        Sb[p*DS + n] = acc[fi][fj][e];
      }
    }
}

// -------- K2: inter-chunk scan (in-place: Schunk -> S_start) --------
__launch_bounds__(256)
__global__ void interchunk_kernel(float* __restrict__ S, const float* __restrict__ las){
  int blk = blockIdx.x;
  int slice = blk & 7; int bh = blk >> 3;
  size_t base = (size_t)bh*NC*(HD*DS) + slice*1024 + threadIdx.x*4;
  float4 run = make_float4(0,0,0,0);
#pragma unroll
  for (int c=0;c<NC;c++){
    float dec = __expf(las[bh*L_ + c*Q + 63]);
    float4 ch = *(float4*)(S + base + c*(HD*DS));
    *(float4*)(S + base + c*(HD*DS)) = run;
    run.x = fmaf(run.x, dec, ch.x);
    run.y = fmaf(run.y, dec, ch.y);
    run.z = fmaf(run.z, dec, ch.z);
    run.w = fmaf(run.w, dec, ch.w);
  }
}

// -------- K3 (MFMA): per-chunk outputs; writes y as single fp16 plane --------
__launch_bounds__(512)
__global__ void chunk_out_mfma(const float* __restrict__ zx,
                               const float* __restrict__ xbc,
                               const float* __restrict__ dts,
                               const float* __restrict__ las,
                               const float* __restrict__ Sstart,
                               const float* __restrict__ Dp,
                               ushort* __restrict__ yS){
  constexpr int OC_HI = 0,      OC_LO = 8192;
  constexpr int OP_HI = 16384,  OP_LO = 24576;
  constexpr int OX_HI = 32768,  OX_LO = 36864;
  constexpr int OG_HI = 40960,  OG_LO = 45056;
  __shared__ ushort LDSU[49152];
  __shared__ float La[64], Dt[64];

  int c = blockIdx.x, hh = blockIdx.y, b = blockIdx.z;
  int tid = threadIdx.x;
  int bh = b*NH + hh;
  const int tbase = bh*L_ + c*Q;
  const float Dh = Dp[hh];
  const int lane = tid & 63, w = tid >> 6;
  const int wr = w >> 2, wc = w & 3;
  const int lr = lane & 15, lk = lane >> 4;

  for (int it = tid; it < 64*32; it += 512){
    int t = it >> 5, n4 = (it & 31) << 2;
    float4 v = *(const float4*)&xbc[(size_t)(b*L_ + c*Q + t)*CONVD + DI + DS + n4];
    float xv[4] = {v.x,v.y,v.z,v.w};
    ushort h[4], l[4];
#pragma unroll
    for (int j=0;j<4;j++){ h[j]=bf16rn(xv[j]); l[j]=bf16rn(xv[j]-bf2f(h[j])); }
    int idx = t*128 + (((n4>>3) ^ (t&7))<<3) + (n4&7);
    *(uint2*)&LDSU[OC_HI + idx] = make_uint2((uint)h[0]|((uint)h[1]<<16), (uint)h[2]|((uint)h[3]<<16));
    *(uint2*)&LDSU[OC_LO + idx] = make_uint2((uint)l[0]|((uint)l[1]<<16), (uint)l[2]|((uint)l[3]<<16));
  }
  const float* Sb = Sstart + ((size_t)bh*NC + c)*(HD*DS);
  for (int it = tid; it < 64*32; it += 512){
    int p = it >> 5, n4 = (it & 31) << 2;
    float4 v = *(const float4*)&Sb[p*DS + n4];
    float xv[4] = {v.x,v.y,v.z,v.w};
    ushort h[4], l[4];
#pragma unroll
    for (int j=0;j<4;j++){ h[j]=bf16rn(xv[j]); l[j]=bf16rn(xv[j]-bf2f(h[j])); }
    int idx = p*128 + (((n4>>3) ^ (p&7))<<3) + (n4&7);
    *(uint2*)&LDSU[OP_HI + idx] = make_uint2((uint)h[0]|((uint)h[1]<<16), (uint)h[2]|((uint)h[3]<<16));
    *(uint2*)&LDSU[OP_LO + idx] = make_uint2((uint)l[0]|((uint)l[1]<<16), (uint)l[2]|((uint)l[3]<<16));
  }
  for (int it = tid; it < 64*16; it += 512){
    int s = it >> 4, p4 = (it & 15) << 2;
    float4 v = *(const float4*)&xbc[(size_t)(b*L_ + c*Q + s)*CONVD + hh*HD + p4];
    float xv[4] = {v.x,v.y,v.z,v.w};
#pragma unroll
    for (int j=0;j<4;j++){
      int p = p4 + j;
      ushort h = bf16rn(xv[j]);
      ushort l = bf16rn(xv[j] - bf2f(h));
      int idx = p*64 + (((s>>3) ^ (p&7))<<3) + (s&7);
      LDSU[OX_HI + idx] = h; LDSU[OX_LO + idx] = l;
    }
  }
  if (tid < 64){ La[tid] = las[tbase + tid]; Dt[tid] = dts[tbase + tid]; }
  __syncthreads();

  f32x4 yi[2] = {}, ev[2] = {}, yv[2] = {};

#pragma unroll
  for (int ks=0; ks<4; ks++){
    bf16x8 ah[2], al[2], bh, bl;
#pragma unroll
    for (int fi=0; fi<2; fi++){
      int R = wr*32 + fi*16 + lr;
      int idx = R*128 + (((ks*4 + lk) ^ (R&7))<<3);
      ah[fi] = *(const bf16x8*)&LDSU[OC_HI + idx];
      al[fi] = *(const bf16x8*)&LDSU[OC_LO + idx];
    }
    { int Rb = wc*16 + lr;
      int idx = Rb*128 + (((ks*4 + lk) ^ (Rb&7))<<3);
      bh = *(const bf16x8*)&LDSU[OP_HI + idx];
      bl = *(const bf16x8*)&LDSU[OP_LO + idx]; }
#pragma unroll
    for (int fi=0; fi<2; fi++){
      yi[fi] = __builtin_amdgcn_mfma_f32_16x16x32_bf16(ah[fi], bh, yi[fi], 0,0,0);
      yi[fi] = __builtin_amdgcn_mfma_f32_16x16x32_bf16(ah[fi], bl, yi[fi], 0,0,0);
      yi[fi] = __builtin_amdgcn_mfma_f32_16x16x32_bf16(al[fi], bh, yi[fi], 0,0,0);
    }
  }
  __syncthreads();

  for (int it = tid; it < 64*32; it += 512){
    int s = it >> 5, n4 = (it & 31) << 2;
    float4 v = *(const float4*)&xbc[(size_t)(b*L_ + c*Q + s)*CONVD + DI + n4];
    float xv[4] = {v.x,v.y,v.z,v.w};
    ushort h[4], l[4];
#pragma unroll
    for (int j=0;j<4;j++){ h[j]=bf16rn(xv[j]); l[j]=bf16rn(xv[j]-bf2f(h[j])); }
    int idx = s*128 + (((n4>>3) ^ (s&7))<<3) + (n4&7);
    *(uint2*)&LDSU[OP_HI + idx] = make_uint2((uint)h[0]|((uint)h[1]<<16), (uint)h[2]|((uint)h[3]<<16));
    *(uint2*)&LDSU[OP_LO + idx] = make_uint2((uint)l[0]|((uint)l[1]<<16), (uint)l[2]|((uint)l[3]<<16));
  }
  __syncthreads();

#pragma unroll
  for (int ks=0; ks<4; ks++){
    bf16x8 ah[2], al[2], bh, bl;
#pragma unroll
    for (int fi=0; fi<2; fi++){
      int R = wr*32 + fi*16 + lr;
      int idx = R*128 + (((ks*4 + lk) ^ (R&7))<<3);
      ah[fi] = *(const bf16x8*)&LDSU[OC_HI + idx];
      al[fi] = *(const bf16x8*)&LDSU[OC_LO + idx];
    }
    { int Rb = wc*16 + lr;
      int idx = Rb*128 + (((ks*4 + lk) ^ (Rb&7))<<3);
      bh = *(const bf16x8*)&LDSU[OP_HI + idx];
      bl = *(const bf16x8*)&LDSU[OP_LO + idx]; }
#pragma unroll
    for (int fi=0; fi<2; fi++){
      ev[fi] = __builtin_amdgcn_mfma_f32_16x16x32_bf16(ah[fi], bh, ev[fi], 0,0,0);
      ev[fi] = __builtin_amdgcn_mfma_f32_16x16x32_bf16(ah[fi], bl, ev[fi], 0,0,0);
      ev[fi] = __builtin_amdgcn_mfma_f32_16x16x32_bf16(al[fi], bh, ev[fi], 0,0,0);
    }
  }

  {
    int s_col = wc*16 + lr;
    float las_s = La[s_col], dt_s = Dt[s_col];
#pragma unroll
    for (int fi=0; fi<2; fi++)
#pragma unroll
      for (int e=0; e<4; e++){
        int t = wr*32 + fi*16 + lk*4 + e;
        float g = 0.f;
        if (s_col <= t) g = __expf(La[t] - las_s) * dt_s * ev[fi][e];
        ushort hg = bf16rn(g);
        ushort lg = bf16rn(g - bf2f(hg));
        int idx = t*64 + (((s_col>>3) ^ (t&7))<<3) + (s_col&7);
        LDSU[OG_HI + idx] = hg; LDSU[OG_LO + idx] = lg;
      }
  }
  __syncthreads();

#pragma unroll
  for (int ks=0; ks<2; ks++){
    bf16x8 ah[2], al[2], bh, bl;
#pragma unroll
    for (int fi=0; fi<2; fi++){
      int R = wr*32 + fi*16 + lr;
      int idx = R*64 + (((ks*4 + lk) ^ (R&7))<<3);
      ah[fi] = *(const bf16x8*)&LDSU[OG_HI + idx];
      al[fi] = *(const bf16x8*)&LDSU[OG_LO + idx];
    }
    { int Rb = wc*16 + lr;
      int idx = Rb*64 + (((ks*4 + lk) ^ (Rb&7))<<3);
      bh = *(const bf16x8*)&LDSU[OX_HI + idx];
      bl = *(const bf16x8*)&LDSU[OX_LO + idx]; }
#pragma unroll
    for (int fi=0; fi<2; fi++){
      yv[fi] = __builtin_amdgcn_mfma_f32_16x16x32_bf16(ah[fi], bh, yv[fi], 0,0,0);
      yv[fi] = __builtin_amdgcn_mfma_f32_16x16x32_bf16(ah[fi], bl, yv[fi], 0,0,0);
      yv[fi] = __builtin_amdgcn_mfma_f32_16x16x32_bf16(al[fi], bh, yv[fi], 0,0,0);
    }
  }
  __syncthreads();

  {
    float* Yf = (float*)&LDSU[OG_HI];
    int p = wc*16 + lr;
#pragma unroll
    for (int fi=0; fi<2; fi++)
#pragma unroll
      for (int e=0; e<4; e++){
        int t = wr*32 + fi*16 + lk*4 + e;
        Yf[t*64 + p] = __expf(La[t])*yi[fi][e] + yv[fi][e];
      }
  }
  __syncthreads();

  {
    const float* Yf = (const float*)&LDSU[OG_HI];
    for (int it = tid; it < 64*16; it += 512){
      int t = it >> 4, p4 = (it & 15) << 2;
      size_t row = (size_t)(b*L_ + c*Q + t);
      float4 x4 = *(const float4*)&xbc[row*CONVD + hh*HD + p4];
      float4 z4 = *(const float4*)&zx[row*ZROW + hh*HD + p4];
      float xx[4] = {x4.x,x4.y,x4.z,x4.w};
      float zz[4] = {z4.x,z4.y,z4.z,z4.w};
      ushort h4[4];
#pragma unroll
      for (int j=0;j<4;j++){
        float y = Yf[t*64 + p4 + j] + Dh*xx[j];
        float o = y * (zz[j] * sigmoidf_(zz[j]));
        h4[j] = f16rn(o);
      }
      size_t o0 = row*(size_t)DI + hh*HD + p4;
      *(uint2*)&yS[o0] = make_uint2((uint)h4[0]|((uint)h4[1]<<16), (uint)h4[2]|((uint)h4[3]<<16));
    }
  }
}

extern "C" void kernel_launch(void* const* d_in, const int* in_sizes, int n_in,
                              void* d_out, int out_size, void* d_ws, size_t ws_size,
                              hipStream_t stream) {
  const float* u       = (const float*)d_in[0];
  const float* W_in    = (const float*)d_in[1];
  const float* conv_w  = (const float*)d_in[2];
  const float* conv_b  = (const float*)d_in[3];
  const float* dt_bias = (const float*)d_in[4];
  const float* A_log   = (const float*)d_in[5];
  const float* D_param = (const float*)d_in[6];
  const float* W_out   = (const float*)d_in[7];
  float* out = (float*)d_out;

  float* ws = (float*)d_ws;
  float* zx     = ws;                                        // ML*ZROW
  float* xbc    = zx   + (size_t)ML*ZROW;                    // ML*CONVD
  float* dts    = xbc  + (size_t)ML*CONVD;                   // 24576
  float* las    = dts  + (size_t)B_*NH*L_;                   // 24576
  float* dtraw  = las  + (size_t)B_*NH*L_;                   // ML*NH
  float* Schunk = dtraw + (size_t)ML*NH;                     // 48*8*8192
  ushort* uH    = (ushort*)(Schunk + (size_t)B_*NH*NC*HD*DS);
  ushort* yS    = uH;                                        // alias (uH: ML*DM, dead after gemm1; yS: ML*DI)
  ushort* WinH  = uH + (size_t)ML*DI;                        // after yS extent
  ushort* WoutH = WinH + (size_t)ZROW*DM;                    // DM*DI halfs

  // 1) one-shot: fp16-convert u, W_in[0:ZROW], W_out; fp32 dt-projection; zero d_out
  {
    int outN4 = out_size/4;
    int total = ML*(DM/4) + ZROW*(DM/4) + DM*(DI/4) + ML*NH + outN4;
    cvt_all<<<(total+255)/256, 256, 0, stream>>>(u, W_in, W_out, uH, WinH, WoutH, dtraw, out, outN4);
  }
  // 2) in-projection GEMM (fp16 single-plane, z + xBC columns only)
  {
    dim3 grid(ML/64, ZROW/64, 1);
    gemm_f16<64,64,DM,1,false><<<grid, 256, 0, stream>>>(uH, WinH, zx, ZROW, ZROW);
  }
  // 3) conv + SiLU (rolling window, 32-t blocks)
  {
    dim3 grid(7, L_/32, B_);
    conv2_kernel<<<grid, 256, 0, stream>>>(zx, conv_w, conv_b, xbc);
  }
  // 4) chunk states (MFMA; wave0 computes dt + cumsum from dtraw)
  {
    dim3 grid(NC, NH, B_);
    chunk_state_mfma<<<grid, 256, 0, stream>>>(dtraw, xbc, dt_bias, A_log, dts, las, Schunk);
  }
  // 5) inter-chunk scan
  interchunk_kernel<<<B_*NH*8, 256, 0, stream>>>(Schunk, las);
  // 6) chunk outputs (MFMA) -> yS fp16 plane
  {
    dim3 grid(NC, NH, B_);
    chunk_out_mfma<<<grid, 512, 0, stream>>>(zx, xbc, dts, las, Schunk, D_param, yS);
  }
  // 7) out-projection GEMM (fp16 single-plane, split-K=4, atomic)
  {
    dim3 grid(ML/64, DM/64, 4);
    gemm_f16<64,64,DI,4,true><<<grid, 256, 0, stream>>>(yS, WoutH, out, DM, DM);
  }
}